// Round 6
// baseline (271.477 us; speedup 1.0000x reference)
//
#include <hip/hip_runtime.h>
#include <hip/hip_bf16.h>
#include <math.h>

#define EPSV 1e-6f
#define LAMBDAV 1e-3f
#define LN_2PI 1.8378770664093453f

__device__ __forceinline__ float bflo(unsigned int u) {
    union { unsigned int i; float f; } x; x.i = u << 16; return x.f;
}
__device__ __forceinline__ float bfhi(unsigned int u) {
    union { unsigned int i; float f; } x; x.i = u & 0xffff0000u; return x.f;
}

// Kernel 1: v[nl, i2, cq] and vT[nl, cq, i2]; w register-resident.
// grid = (288 i2, chunks of 32 positions); block = 256 (thread = (c1,q1), 2 c-halves).
__global__ __launch_bounds__(256)
void conv_v_kernel(const float* __restrict__ x, const float* __restrict__ w,
                   __hip_bfloat16* __restrict__ vout,
                   __hip_bfloat16* __restrict__ vtout,
                   int n0, int cnt)
{
    __shared__ float pv[32 * 16];

    const int i2  = blockIdx.x;
    const int kb0 = blockIdx.y * 32;
    const int tid = threadIdx.x;
    const int c1 = tid >> 4, q1 = tid & 15;

    // w[i2][c][p][q] -> regs: lanes vary q1 -> coalesced 64B segments
    const float* wp0 = w + (size_t)i2 * 8192 + c1 * 256 + q1;
    const float* wp1 = wp0 + 16 * 256;
    float wa[16], wb[16];
    #pragma unroll
    for (int p = 0; p < 16; ++p) { wa[p] = wp0[p * 16]; wb[p] = wp1[p * 16]; }

    // gather 32 positions x 16 p into LDS
    #pragma unroll
    for (int u = 0; u < 2; ++u) {
        int idx = u * 256 + tid;
        int k = idx >> 4, p = idx & 15;
        // reference reshape scramble: g=i2*16+p; k2=g>>9; c2=g&511; f=k2*544+c2=ci*9+kk
        int e  = i2 * 16 + p;
        int k2 = e >> 9, c2 = e & 511;
        int f  = k2 * 544 + c2;
        int ci = f / 9, kk = f - ci * 9;
        int nn = n0 + kb0 + k;
        float val = 0.f;
        if (kb0 + k < cnt) {
            int bi = nn >> 6, oi = (nn >> 3) & 7, oj = nn & 7;
            int row = 2 * oi + kk / 3 - 1;
            int col = 2 * oj + (kk - (kk / 3) * 3) - 1;
            if ((unsigned)row < 16u && (unsigned)col < 16u)
                val = x[((bi * 16 + row) * 16 + col) * 544 + ci];
        }
        pv[k * 16 + p] = val;
    }
    __syncthreads();

    const int kmax = min(32, cnt - kb0);
    for (int k = 0; k < kmax; ++k) {
        const float4 pa = *(const float4*)&pv[k * 16];
        const float4 pb = *(const float4*)&pv[k * 16 + 4];
        const float4 pc = *(const float4*)&pv[k * 16 + 8];
        const float4 pd = *(const float4*)&pv[k * 16 + 12];
        float acc0, acc1;
        acc0  = pa.x * wa[0]  + pa.y * wa[1]  + pa.z * wa[2]  + pa.w * wa[3];
        acc0 += pb.x * wa[4]  + pb.y * wa[5]  + pb.z * wa[6]  + pb.w * wa[7];
        acc0 += pc.x * wa[8]  + pc.y * wa[9]  + pc.z * wa[10] + pc.w * wa[11];
        acc0 += pd.x * wa[12] + pd.y * wa[13] + pd.z * wa[14] + pd.w * wa[15];
        acc1  = pa.x * wb[0]  + pa.y * wb[1]  + pa.z * wb[2]  + pa.w * wb[3];
        acc1 += pb.x * wb[4]  + pb.y * wb[5]  + pb.z * wb[6]  + pb.w * wb[7];
        acc1 += pc.x * wb[8]  + pc.y * wb[9]  + pc.z * wb[10] + pc.w * wb[11];
        acc1 += pd.x * wb[12] + pd.y * wb[13] + pd.z * wb[14] + pd.w * wb[15];
        const int nl = kb0 + k;
        __hip_bfloat16 b0 = __float2bfloat16(acc0);
        __hip_bfloat16 b1 = __float2bfloat16(acc1);
        vout[((size_t)nl * 288 + i2) * 512 + tid]       = b0;
        vout[((size_t)nl * 288 + i2) * 512 + tid + 256] = b1;
        vtout[((size_t)nl * 512 + c1 * 16 + q1) * 288 + i2]        = b0;
        vtout[((size_t)nl * 512 + (c1 + 16) * 16 + q1) * 288 + i2] = b1;
    }
}

// Kernel 2: EM routing. Block = 1024 per position. mu/sigma via vT (contiguous
// uint4), ln_ap via v (coalesced uint4), softmax fused with rr + column partials.
__global__ __launch_bounds__(1024)
void em_routing_kernel(const float* __restrict__ x,
                       const unsigned short* __restrict__ v,    // [n][i][cq] bf16
                       const unsigned short* __restrict__ vT,   // [n][cq][i] bf16
                       const float* __restrict__ beta_u,
                       const float* __restrict__ beta_a,
                       float* __restrict__ out, int n0)
{
    __shared__ float r_s[288 * 33];     // rr / ln_ap, stride 33
    __shared__ float fct_s[288];        // a/(a+eps)
    __shared__ float part_s[32 * 33];   // column partials per 32-row group
    __shared__ float rsum_s[32];
    __shared__ float mu_s[32 * 17];
    __shared__ float i2ss_s[32 * 17];
    __shared__ float hlog_s[32 * 17];
    __shared__ float aout_s[32];
    __shared__ float kc_s[32];
    __shared__ float p0_s[512], p1_s[512], p2_s[512];

    const int n   = n0 + blockIdx.x;
    const int tid = threadIdx.x;
    const int bi = n >> 6, oi = (n >> 3) & 7, oj = n & 7;

    if (tid < 288) {
        // a_in gather: c2 in [512,544)
        int k2 = tid >> 5;
        int c2 = 512 + (tid & 31);
        int f  = k2 * 544 + c2;
        int ci = f / 9;
        int kk = f - ci * 9;
        int row = 2 * oi + kk / 3 - 1;
        int col = 2 * oj + (kk - (kk / 3) * 3) - 1;
        float a = 0.f;
        if ((unsigned)row < 16u && (unsigned)col < 16u)
            a = x[((bi * 16 + row) * 16 + col) * 544 + ci];
        fct_s[tid] = a / (a + EPSV);   // sum_c(r*a) == a exactly -> rr = r*fct
    }
    __syncthreads();

    const unsigned short* vb  = v  + (size_t)blockIdx.x * 288 * 512;
    const unsigned short* vtb = vT + (size_t)blockIdx.x * 288 * 512;

    const int lane_c = tid & 31;   // row phases
    const int row0   = tid >> 5;
    const int cc  = tid >> 5;      // mu phase
    const int rem = tid & 31;
    const int hh  = rem >> 4;
    const int qq  = rem & 15;

    // t=0: r uniform -> rr = fct/32; populate r_s + column partials directly
    {
        float ps = 0.f;
        #pragma unroll
        for (int k = 0; k < 9; ++k) {
            int i = k * 32 + row0;
            float rr0 = fct_s[i] * 0.03125f;
            r_s[i * 33 + lane_c] = rr0;
            ps += rr0;
        }
        part_s[row0 * 33 + lane_c] = ps;
    }
    __syncthreads();

    for (int t = 0; t < 3; ++t) {
        // --- mu/sigma: inline rsum shuffle-reduce, vT contiguous uint4 loads ---
        float s0 = 0.f, s1 = 0.f, s2 = 0.f;
        {
            float pp = part_s[rem * 33 + cc];
            pp += __shfl_xor(pp, 1, 32);
            pp += __shfl_xor(pp, 2, 32);
            pp += __shfl_xor(pp, 4, 32);
            pp += __shfl_xor(pp, 8, 32);
            pp += __shfl_xor(pp, 16, 32);
            if (rem == 0) rsum_s[cc] = pp;
            const float invr = 1.0f / (pp + EPSV);

            const int ib = hh * 144;
            const uint4* vt4 = (const uint4*)(vtb + (size_t)(cc * 16 + qq) * 288 + ib);
            #pragma unroll
            for (int j = 0; j < 18; ++j) {
                uint4 u = vt4[j];
                const float* rr = &r_s[(ib + j * 8) * 33 + cc];
                float co, vv;
                co = rr[0]   * invr; vv = bflo(u.x); s0 += co; s1 += co * vv; s2 += co * vv * vv;
                co = rr[33]  * invr; vv = bfhi(u.x); s0 += co; s1 += co * vv; s2 += co * vv * vv;
                co = rr[66]  * invr; vv = bflo(u.y); s0 += co; s1 += co * vv; s2 += co * vv * vv;
                co = rr[99]  * invr; vv = bfhi(u.y); s0 += co; s1 += co * vv; s2 += co * vv * vv;
                co = rr[132] * invr; vv = bflo(u.z); s0 += co; s1 += co * vv; s2 += co * vv * vv;
                co = rr[165] * invr; vv = bfhi(u.z); s0 += co; s1 += co * vv; s2 += co * vv * vv;
                co = rr[198] * invr; vv = bflo(u.w); s0 += co; s1 += co * vv; s2 += co * vv * vv;
                co = rr[231] * invr; vv = bfhi(u.w); s0 += co; s1 += co * vv; s2 += co * vv * vv;
            }
            if (hh == 1) {
                p0_s[cc * 16 + qq] = s0;
                p1_s[cc * 16 + qq] = s1;
                p2_s[cc * 16 + qq] = s2;
            }
        }
        __syncthreads();

        if (hh == 0) {
            s0 += p0_s[cc * 16 + qq];
            s1 += p1_s[cc * 16 + qq];
            s2 += p2_s[cc * 16 + qq];
            float mu  = s1;
            float sig = s2 - s1 * s1 * (2.0f - s0);   // == sum co*(v-mu)^2 exactly
            sig = fmaxf(sig + EPSV, 1e-4f);
            float hl = 0.5f * logf(sig);
            mu_s[cc * 17 + qq]   = mu;
            hlog_s[cc * 17 + qq] = hl;
            i2ss_s[cc * 17 + qq] = 1.0f / (2.0f * sig);
        }
        __syncthreads();

        // --- a_out + per-c ln_p constant ---
        if (tid < 32) {
            float cs = 0.f, shl = 0.f;
            float bu = beta_u[tid];
            #pragma unroll
            for (int q = 0; q < 16; ++q) { float hl = hlog_s[tid * 17 + q]; shl += hl; cs += bu + hl; }
            cs *= rsum_s[tid];
            float arg = LAMBDAV * (beta_a[tid] - cs);
            float ao  = 1.0f / (1.0f + expf(-arg));
            ao = fminf(fmaxf(ao, 1e-4f), 1.0f - 1e-4f);
            aout_s[tid] = ao;
            kc_s[tid]   = logf(ao + EPSV) - shl - 8.0f * LN_2PI;
        }
        __syncthreads();

        if (t < 2) {
            // --- ln_ap[i][c] = kc[c] - sum_q (v-mu)^2*i2ss  (original v layout) ---
            #pragma unroll
            for (int it = 0; it < 9; ++it) {
                int idx = it * 1024 + tid;
                int i = idx >> 5, c = idx & 31;
                const uint4* vp4 = (const uint4*)(vb + (size_t)i * 512 + c * 16);
                uint4 u0 = vp4[0], u1 = vp4[1];
                const float* mrow = &mu_s[c * 17];
                const float* irow = &i2ss_s[c * 17];
                float acc = kc_s[c];
                float d;
                d = bflo(u0.x) - mrow[0];   acc -= d * d * irow[0];
                d = bfhi(u0.x) - mrow[1];   acc -= d * d * irow[1];
                d = bflo(u0.y) - mrow[2];   acc -= d * d * irow[2];
                d = bfhi(u0.y) - mrow[3];   acc -= d * d * irow[3];
                d = bflo(u0.z) - mrow[4];   acc -= d * d * irow[4];
                d = bfhi(u0.z) - mrow[5];   acc -= d * d * irow[5];
                d = bflo(u0.w) - mrow[6];   acc -= d * d * irow[6];
                d = bfhi(u0.w) - mrow[7];   acc -= d * d * irow[7];
                d = bflo(u1.x) - mrow[8];   acc -= d * d * irow[8];
                d = bfhi(u1.x) - mrow[9];   acc -= d * d * irow[9];
                d = bflo(u1.y) - mrow[10];  acc -= d * d * irow[10];
                d = bfhi(u1.y) - mrow[11];  acc -= d * d * irow[11];
                d = bflo(u1.z) - mrow[12];  acc -= d * d * irow[12];
                d = bfhi(u1.z) - mrow[13];  acc -= d * d * irow[13];
                d = bflo(u1.w) - mrow[14];  acc -= d * d * irow[14];
                d = bfhi(u1.w) - mrow[15];  acc -= d * d * irow[15];
                r_s[i * 33 + c] = acc;
            }
            __syncthreads();

            // --- fused softmax -> rr -> column partials ---
            // r = e/sum(e); rr = r*a/(sum_c r*a + eps) = r*fct (sum_c r*a == a)
            {
                float ps = 0.f;
                #pragma unroll
                for (int k = 0; k < 9; ++k) {
                    int i = k * 32 + row0;
                    float val = r_s[i * 33 + lane_c];
                    float mx = val;
                    mx = fmaxf(mx, __shfl_xor(mx, 1, 32));
                    mx = fmaxf(mx, __shfl_xor(mx, 2, 32));
                    mx = fmaxf(mx, __shfl_xor(mx, 4, 32));
                    mx = fmaxf(mx, __shfl_xor(mx, 8, 32));
                    mx = fmaxf(mx, __shfl_xor(mx, 16, 32));
                    float e = expf(val - mx);
                    float se = e;
                    se += __shfl_xor(se, 1, 32);
                    se += __shfl_xor(se, 2, 32);
                    se += __shfl_xor(se, 4, 32);
                    se += __shfl_xor(se, 8, 32);
                    se += __shfl_xor(se, 16, 32);
                    float rrv = (e / se) * fct_s[i];
                    r_s[i * 33 + lane_c] = rrv;
                    ps += rrv;
                }
                part_s[row0 * 33 + lane_c] = ps;
            }
            __syncthreads();
        }
    }

    // epilogue (fp32): p_out [0,65536) | a_out [65536,69632) | out [69632,139264)
    if (tid < 512) {
        int c = tid >> 4, q = tid & 15;
        float mu = mu_s[c * 17 + q];
        if (isnan(mu)) mu = 0.f;
        mu = fminf(fmaxf(mu, -10000.f), 10000.f);
        out[(size_t)n * 512 + tid] = mu;
        out[69632 + (size_t)n * 544 + tid] = mu;
        if (tid < 32) {
            float ao = aout_s[tid];
            if (isnan(ao)) ao = 0.5f;
            out[65536 + n * 32 + tid] = ao;
            out[69632 + n * 544 + 512 + tid] = ao;
        }
    }
}

extern "C" void kernel_launch(void* const* d_in, const int* in_sizes, int n_in,
                              void* d_out, int out_size, void* d_ws, size_t ws_size,
                              hipStream_t stream) {
    const float* x  = (const float*)d_in[0];
    const float* w  = (const float*)d_in[1];
    const float* bu = (const float*)d_in[2];
    const float* ba = (const float*)d_in[3];
    float* out = (float*)d_out;

    // ws: v (CN*288*512 bf16) then vT (CN*512*288 bf16)
    const size_t per_n = (size_t)288 * 512 * 2 * 2;   // 589824 B (both layouts)
    int CN = (int)(ws_size / per_n);
    if (CN < 1)   CN = 1;
    if (CN > 128) CN = 128;
    __hip_bfloat16* v  = (__hip_bfloat16*)d_ws;
    __hip_bfloat16* vT = v + (size_t)CN * 288 * 512;

    for (int ncur = 0; ncur < 128; ncur += CN) {
        int cnt = (128 - ncur < CN) ? (128 - ncur) : CN;
        conv_v_kernel<<<dim3(288, (cnt + 31) / 32), dim3(256), 0, stream>>>(
            x, w, v, vT, ncur, cnt);
        em_routing_kernel<<<dim3(cnt), dim3(1024), 0, stream>>>(
            x, (const unsigned short*)v, (const unsigned short*)vT, bu, ba, out, ncur);
    }
}

// Round 7
// 217.068 us; speedup vs baseline: 1.2507x; 1.2507x over previous
//
#include <hip/hip_runtime.h>
#include <hip/hip_bf16.h>
#include <math.h>

#define EPSV 1e-6f
#define LAMBDAV 1e-3f
#define LN_2PI 1.8378770664093453f

__device__ __forceinline__ float bflo(unsigned int u) {
    union { unsigned int i; float f; } x; x.i = u << 16; return x.f;
}
__device__ __forceinline__ float bfhi(unsigned int u) {
    union { unsigned int i; float f; } x; x.i = u & 0xffff0000u; return x.f;
}

// Kernel 1: v[nl, i2, cq] bf16, register-resident w, v-only (no transpose).
// grid = (288 i2, chunks of 32 positions); block = 256 (thread = (c1,q1), 2 c-halves).
__global__ __launch_bounds__(256)
void conv_v_kernel(const float* __restrict__ x, const float* __restrict__ w,
                   __hip_bfloat16* __restrict__ vout, int n0, int cnt)
{
    __shared__ float pv[32 * 16];

    const int i2  = blockIdx.x;
    const int kb0 = blockIdx.y * 32;
    const int tid = threadIdx.x;
    const int c1 = tid >> 4, q1 = tid & 15;

    // w[i2][c][p][q] -> regs (lanes vary q1 -> coalesced)
    const float* wp0 = w + (size_t)i2 * 8192 + c1 * 256 + q1;
    const float* wp1 = wp0 + 16 * 256;
    float wa[16], wb[16];
    #pragma unroll
    for (int p = 0; p < 16; ++p) { wa[p] = wp0[p * 16]; wb[p] = wp1[p * 16]; }

    // gather 32 positions x 16 p into LDS
    #pragma unroll
    for (int u = 0; u < 2; ++u) {
        int idx = u * 256 + tid;
        int k = idx >> 4, p = idx & 15;
        // reference reshape scramble: g=i2*16+p; k2=g>>9; c2=g&511; f=k2*544+c2=ci*9+kk
        int e  = i2 * 16 + p;
        int k2 = e >> 9, c2 = e & 511;
        int f  = k2 * 544 + c2;
        int ci = f / 9, kk = f - ci * 9;
        int nn = n0 + kb0 + k;
        float val = 0.f;
        if (kb0 + k < cnt) {
            int bi = nn >> 6, oi = (nn >> 3) & 7, oj = nn & 7;
            int row = 2 * oi + kk / 3 - 1;
            int col = 2 * oj + (kk - (kk / 3) * 3) - 1;
            if ((unsigned)row < 16u && (unsigned)col < 16u)
                val = x[((bi * 16 + row) * 16 + col) * 544 + ci];
        }
        pv[k * 16 + p] = val;
    }
    __syncthreads();

    const int kmax = min(32, cnt - kb0);
    for (int k = 0; k < kmax; ++k) {
        const float4 pa = *(const float4*)&pv[k * 16];
        const float4 pb = *(const float4*)&pv[k * 16 + 4];
        const float4 pc = *(const float4*)&pv[k * 16 + 8];
        const float4 pd = *(const float4*)&pv[k * 16 + 12];
        float acc0, acc1;
        acc0  = pa.x * wa[0]  + pa.y * wa[1]  + pa.z * wa[2]  + pa.w * wa[3];
        acc0 += pb.x * wa[4]  + pb.y * wa[5]  + pb.z * wa[6]  + pb.w * wa[7];
        acc0 += pc.x * wa[8]  + pc.y * wa[9]  + pc.z * wa[10] + pc.w * wa[11];
        acc0 += pd.x * wa[12] + pd.y * wa[13] + pd.z * wa[14] + pd.w * wa[15];
        acc1  = pa.x * wb[0]  + pa.y * wb[1]  + pa.z * wb[2]  + pa.w * wb[3];
        acc1 += pb.x * wb[4]  + pb.y * wb[5]  + pb.z * wb[6]  + pb.w * wb[7];
        acc1 += pc.x * wb[8]  + pc.y * wb[9]  + pc.z * wb[10] + pc.w * wb[11];
        acc1 += pd.x * wb[12] + pd.y * wb[13] + pd.z * wb[14] + pd.w * wb[15];
        const int nl = kb0 + k;
        __hip_bfloat16* vp = vout + ((size_t)nl * 288 + i2) * 512;
        vp[tid]       = __float2bfloat16(acc0);
        vp[tid + 256] = __float2bfloat16(acc1);
    }
}

// Kernel 2: EM routing, fused single-sweep per iteration.
// Block = 1024 per position. Half-wave hw (=tid>>5) owns rows {hw+32k}; lane c.
// Per row: load v row segment (2 uint4), ln_ap, shuffle-softmax over c, rr,
// accumulate S0/S1[16]/S2[16] in registers. No stored r matrix, no vT.
__global__ __launch_bounds__(1024)
void em_routing_kernel(const float* __restrict__ x,
                       const unsigned short* __restrict__ v,   // [n][i][cq] bf16
                       const float* __restrict__ beta_u,
                       const float* __restrict__ beta_a,
                       float* __restrict__ out, int n0)
{
    __shared__ float fct_s[288];          // a/(a+eps)
    __shared__ float red_s[16 * 32 * 33]; // [wave][c][{S0,S1[16],S2[16]}] 67.6 KB
    __shared__ float mu_s[32 * 17];
    __shared__ float i2ss_s[32 * 17];
    __shared__ float hlog_s[32 * 17];
    __shared__ float rsum_s[32];
    __shared__ float aout_s[32];
    __shared__ float kc_s[32];

    const int n   = n0 + blockIdx.x;
    const int tid = threadIdx.x;
    const int bi = n >> 6, oi = (n >> 3) & 7, oj = n & 7;

    if (tid < 288) {
        // a_in gather: c2 in [512,544)
        int k2 = tid >> 5;
        int c2 = 512 + (tid & 31);
        int f  = k2 * 544 + c2;
        int ci = f / 9;
        int kk = f - ci * 9;
        int row = 2 * oi + kk / 3 - 1;
        int col = 2 * oj + (kk - (kk / 3) * 3) - 1;
        float a = 0.f;
        if ((unsigned)row < 16u && (unsigned)col < 16u)
            a = x[((bi * 16 + row) * 16 + col) * 544 + ci];
        fct_s[tid] = a / (a + EPSV);   // sum_c r*a == a -> rr = softmax * fct
    }
    __syncthreads();

    const unsigned short* vb = v + (size_t)blockIdx.x * 288 * 512;
    const int lane = tid & 63;
    const int wv   = tid >> 6;     // wave 0..15
    const int hw   = tid >> 5;     // half-wave 0..31
    const int c    = tid & 31;     // lane-c within half-wave

    for (int t = 0; t < 3; ++t) {
        float s0 = 0.f;
        float s1[16], s2[16];
        #pragma unroll
        for (int q = 0; q < 16; ++q) { s1[q] = 0.f; s2[q] = 0.f; }

        #pragma unroll
        for (int k = 0; k < 9; ++k) {
            const int i = k * 32 + hw;
            const uint4* vp4 = (const uint4*)(vb + (size_t)i * 512 + c * 16);
            uint4 u0 = vp4[0], u1 = vp4[1];
            float vv[16];
            vv[0]  = bflo(u0.x); vv[1]  = bfhi(u0.x);
            vv[2]  = bflo(u0.y); vv[3]  = bfhi(u0.y);
            vv[4]  = bflo(u0.z); vv[5]  = bfhi(u0.z);
            vv[6]  = bflo(u0.w); vv[7]  = bfhi(u0.w);
            vv[8]  = bflo(u1.x); vv[9]  = bfhi(u1.x);
            vv[10] = bflo(u1.y); vv[11] = bfhi(u1.y);
            vv[12] = bflo(u1.z); vv[13] = bfhi(u1.z);
            vv[14] = bflo(u1.w); vv[15] = bfhi(u1.w);

            float rrv;
            if (t == 0) {
                rrv = fct_s[i] * 0.03125f;   // uniform r
            } else {
                const float* mrow = &mu_s[c * 17];
                const float* irow = &i2ss_s[c * 17];
                float acc = kc_s[c];
                #pragma unroll
                for (int q = 0; q < 16; ++q) {
                    float d = vv[q] - mrow[q];
                    acc -= d * d * irow[q];
                }
                // softmax over c (32 lanes of this half-wave)
                float mx = acc;
                mx = fmaxf(mx, __shfl_xor(mx, 1, 32));
                mx = fmaxf(mx, __shfl_xor(mx, 2, 32));
                mx = fmaxf(mx, __shfl_xor(mx, 4, 32));
                mx = fmaxf(mx, __shfl_xor(mx, 8, 32));
                mx = fmaxf(mx, __shfl_xor(mx, 16, 32));
                float e = expf(acc - mx);
                float se = e;
                se += __shfl_xor(se, 1, 32);
                se += __shfl_xor(se, 2, 32);
                se += __shfl_xor(se, 4, 32);
                se += __shfl_xor(se, 8, 32);
                se += __shfl_xor(se, 16, 32);
                rrv = (e / se) * fct_s[i];
            }

            s0 += rrv;
            #pragma unroll
            for (int q = 0; q < 16; ++q) {
                s1[q] += rrv * vv[q];
                s2[q] += rrv * vv[q] * vv[q];
            }
        }

        // combine the wave's two half-waves (rows differ, same c)
        s0 += __shfl_xor(s0, 32, 64);
        #pragma unroll
        for (int q = 0; q < 16; ++q) {
            s1[q] += __shfl_xor(s1[q], 32, 64);
            s2[q] += __shfl_xor(s2[q], 32, 64);
        }
        if (lane < 32) {
            float* dst = &red_s[(wv * 32 + lane) * 33];
            dst[0] = s0;
            #pragma unroll
            for (int q = 0; q < 16; ++q) { dst[1 + q] = s1[q]; dst[17 + q] = s2[q]; }
        }
        __syncthreads();

        // final 16-way reduce + mu/sigma (thread = (c2,q2))
        if (tid < 512) {
            int c2 = tid >> 4, q2 = tid & 15;
            float S0 = 0.f, S1 = 0.f, S2 = 0.f;
            #pragma unroll
            for (int wvi = 0; wvi < 16; ++wvi) {
                const float* src = &red_s[(wvi * 32 + c2) * 33];
                S0 += src[0];
                S1 += src[1 + q2];
                S2 += src[17 + q2];
            }
            if (q2 == 0) rsum_s[c2] = S0;
            float invr = 1.0f / (S0 + EPSV);
            float w0 = S0 * invr;
            float m  = S1 * invr;
            float s2p = S2 * invr;
            float sig = s2p - m * m * (2.0f - w0);   // == sum coeff*(v-mu)^2
            sig = fmaxf(sig + EPSV, 1e-4f);
            float hl = 0.5f * logf(sig);
            mu_s[c2 * 17 + q2]   = m;
            hlog_s[c2 * 17 + q2] = hl;
            i2ss_s[c2 * 17 + q2] = 1.0f / (2.0f * sig);
        }
        __syncthreads();

        // a_out + per-c ln_p constant
        if (tid < 32) {
            float cs = 0.f, shl = 0.f;
            float bu = beta_u[tid];
            #pragma unroll
            for (int q = 0; q < 16; ++q) { float hl = hlog_s[tid * 17 + q]; shl += hl; cs += bu + hl; }
            cs *= rsum_s[tid];
            float arg = LAMBDAV * (beta_a[tid] - cs);
            float ao  = 1.0f / (1.0f + expf(-arg));
            ao = fminf(fmaxf(ao, 1e-4f), 1.0f - 1e-4f);
            aout_s[tid] = ao;
            kc_s[tid]   = logf(ao + EPSV) - shl - 8.0f * LN_2PI;
        }
        __syncthreads();
    }

    // epilogue (fp32): p_out [0,65536) | a_out [65536,69632) | out [69632,139264)
    if (tid < 512) {
        int c2 = tid >> 4, q2 = tid & 15;
        float mu = mu_s[c2 * 17 + q2];
        if (isnan(mu)) mu = 0.f;
        mu = fminf(fmaxf(mu, -10000.f), 10000.f);
        out[(size_t)n * 512 + tid] = mu;
        out[69632 + (size_t)n * 544 + tid] = mu;
        if (tid < 32) {
            float ao = aout_s[tid];
            if (isnan(ao)) ao = 0.5f;
            out[65536 + n * 32 + tid] = ao;
            out[69632 + n * 544 + 512 + tid] = ao;
        }
    }
}

extern "C" void kernel_launch(void* const* d_in, const int* in_sizes, int n_in,
                              void* d_out, int out_size, void* d_ws, size_t ws_size,
                              hipStream_t stream) {
    const float* x  = (const float*)d_in[0];
    const float* w  = (const float*)d_in[1];
    const float* bu = (const float*)d_in[2];
    const float* ba = (const float*)d_in[3];
    float* out = (float*)d_out;
    __hip_bfloat16* v = (__hip_bfloat16*)d_ws;  // 128*288*512 bf16 = 37.7 MB

    const size_t per_n = (size_t)288 * 512 * sizeof(__hip_bfloat16); // 294912 B
    int CN = (int)(ws_size / per_n);
    if (CN < 1)   CN = 1;
    if (CN > 128) CN = 128;

    for (int ncur = 0; ncur < 128; ncur += CN) {
        int cnt = (128 - ncur < CN) ? (128 - ncur) : CN;
        conv_v_kernel<<<dim3(288, (cnt + 31) / 32), dim3(256), 0, stream>>>(
            x, w, v, ncur, cnt);
        em_routing_kernel<<<dim3(cnt), dim3(1024), 0, stream>>>(
            x, (const unsigned short*)v, bu, ba, out, ncur);
    }
}

// Round 8
// 140.142 us; speedup vs baseline: 1.9372x; 1.5489x over previous
//
#include <hip/hip_runtime.h>
#include <hip/hip_bf16.h>
#include <math.h>

#define EPSV 1e-6f
#define LAMBDAV 1e-3f
#define LN_2PI 1.8378770664093453f

__device__ __forceinline__ float bflo(unsigned int u) {
    union { unsigned int i; float f; } x; x.i = u << 16; return x.f;
}
__device__ __forceinline__ float bfhi(unsigned int u) {
    union { unsigned int i; float f; } x; x.i = u & 0xffff0000u; return x.f;
}

// Kernel 1: v[nl, i2, cq] bf16, register-resident w.
// grid = (288 i2, chunks of 32 positions); block = 256 (thread = (c1,q1), 2 c-halves).
__global__ __launch_bounds__(256)
void conv_v_kernel(const float* __restrict__ x, const float* __restrict__ w,
                   __hip_bfloat16* __restrict__ vout, int n0, int cnt)
{
    __shared__ float pv[32 * 16];

    const int i2  = blockIdx.x;
    const int kb0 = blockIdx.y * 32;
    const int tid = threadIdx.x;
    const int c1 = tid >> 4, q1 = tid & 15;

    const float* wp0 = w + (size_t)i2 * 8192 + c1 * 256 + q1;
    const float* wp1 = wp0 + 16 * 256;
    float wa[16], wb[16];
    #pragma unroll
    for (int p = 0; p < 16; ++p) { wa[p] = wp0[p * 16]; wb[p] = wp1[p * 16]; }

    #pragma unroll
    for (int u = 0; u < 2; ++u) {
        int idx = u * 256 + tid;
        int k = idx >> 4, p = idx & 15;
        // reference reshape scramble: g=i2*16+p; k2=g>>9; c2=g&511; f=k2*544+c2=ci*9+kk
        int e  = i2 * 16 + p;
        int k2 = e >> 9, c2 = e & 511;
        int f  = k2 * 544 + c2;
        int ci = f / 9, kk = f - ci * 9;
        int nn = n0 + kb0 + k;
        float val = 0.f;
        if (kb0 + k < cnt) {
            int bi = nn >> 6, oi = (nn >> 3) & 7, oj = nn & 7;
            int row = 2 * oi + kk / 3 - 1;
            int col = 2 * oj + (kk - (kk / 3) * 3) - 1;
            if ((unsigned)row < 16u && (unsigned)col < 16u)
                val = x[((bi * 16 + row) * 16 + col) * 544 + ci];
        }
        pv[k * 16 + p] = val;
    }
    __syncthreads();

    const int kmax = min(32, cnt - kb0);
    for (int k = 0; k < kmax; ++k) {
        const float4 pa = *(const float4*)&pv[k * 16];
        const float4 pb = *(const float4*)&pv[k * 16 + 4];
        const float4 pc = *(const float4*)&pv[k * 16 + 8];
        const float4 pd = *(const float4*)&pv[k * 16 + 12];
        float acc0, acc1;
        acc0  = pa.x * wa[0]  + pa.y * wa[1]  + pa.z * wa[2]  + pa.w * wa[3];
        acc0 += pb.x * wa[4]  + pb.y * wa[5]  + pb.z * wa[6]  + pb.w * wa[7];
        acc0 += pc.x * wa[8]  + pc.y * wa[9]  + pc.z * wa[10] + pc.w * wa[11];
        acc0 += pd.x * wa[12] + pd.y * wa[13] + pd.z * wa[14] + pd.w * wa[15];
        acc1  = pa.x * wb[0]  + pa.y * wb[1]  + pa.z * wb[2]  + pa.w * wb[3];
        acc1 += pb.x * wb[4]  + pb.y * wb[5]  + pb.z * wb[6]  + pb.w * wb[7];
        acc1 += pc.x * wb[8]  + pc.y * wb[9]  + pc.z * wb[10] + pc.w * wb[11];
        acc1 += pd.x * wb[12] + pd.y * wb[13] + pd.z * wb[14] + pd.w * wb[15];
        const int nl = kb0 + k;
        __hip_bfloat16* vp = vout + ((size_t)nl * 288 + i2) * 512;
        vp[tid]       = __float2bfloat16(acc0);
        vp[tid + 256] = __float2bfloat16(acc1);
    }
}

// Kernel 2: EM routing, fused single sweep, q split across wave halves.
// Block = 1024 = 16 waves. Lane = (qh = lane>>5, c = lane&31); each lane owns
// 8 q's (one uint4 row read). Wave w handles rows {w + 16k}, k<18.
// Accumulators s0,s1[8],s2[8] + cached mu/i2ss[8] stay in registers
// (__launch_bounds__(1024,4) -> 128-VGPR cap, no scratch spills).
__global__ __launch_bounds__(1024, 4)
void em_routing_kernel(const float* __restrict__ x,
                       const unsigned short* __restrict__ v,   // [n][i][cq] bf16
                       const float* __restrict__ beta_u,
                       const float* __restrict__ beta_a,
                       float* __restrict__ out, int n0)
{
    __shared__ float fct_s[288];            // a/(a+eps)
    __shared__ float red_s[16 * 64 * 17];   // [wave][lane][s0|s1[8]|s2[8]] 69.6 KB
    __shared__ float mu_s[32 * 17];
    __shared__ float i2ss_s[32 * 17];
    __shared__ float hlog_s[32 * 17];
    __shared__ float rsum_s[32];
    __shared__ float aout_s[32];
    __shared__ float kc_s[32];

    const int n   = n0 + blockIdx.x;
    const int tid = threadIdx.x;
    const int bi = n >> 6, oi = (n >> 3) & 7, oj = n & 7;

    if (tid < 288) {
        // a_in gather: c2 in [512,544)
        int k2 = tid >> 5;
        int c2 = 512 + (tid & 31);
        int f  = k2 * 544 + c2;
        int ci = f / 9;
        int kk = f - ci * 9;
        int row = 2 * oi + kk / 3 - 1;
        int col = 2 * oj + (kk - (kk / 3) * 3) - 1;
        float a = 0.f;
        if ((unsigned)row < 16u && (unsigned)col < 16u)
            a = x[((bi * 16 + row) * 16 + col) * 544 + ci];
        fct_s[tid] = a / (a + EPSV);   // sum_c r*a == a -> rr = softmax * fct
    }
    __syncthreads();

    const unsigned short* vb = v + (size_t)blockIdx.x * 288 * 512;
    const int wv   = tid >> 6;      // wave 0..15
    const int lane = tid & 63;
    const int c    = lane & 31;
    const int qh   = lane >> 5;     // q-half 0/1
    const int qb   = qh * 8;

    for (int t = 0; t < 3; ++t) {
        float mu8[8], is8[8], kcv = 0.f;
        if (t > 0) {
            #pragma unroll
            for (int j = 0; j < 8; ++j) {
                mu8[j] = mu_s[c * 17 + qb + j];
                is8[j] = i2ss_s[c * 17 + qb + j];
            }
            kcv = kc_s[c];
        }

        float s0 = 0.f, s1[8], s2[8];
        #pragma unroll
        for (int j = 0; j < 8; ++j) { s1[j] = 0.f; s2[j] = 0.f; }

        #pragma unroll 2
        for (int k = 0; k < 18; ++k) {
            const int i = k * 16 + wv;
            uint4 u = *(const uint4*)(vb + (size_t)i * 512 + c * 16 + qb);
            float vv[8];
            vv[0] = bflo(u.x); vv[1] = bfhi(u.x);
            vv[2] = bflo(u.y); vv[3] = bfhi(u.y);
            vv[4] = bflo(u.z); vv[5] = bfhi(u.z);
            vv[6] = bflo(u.w); vv[7] = bfhi(u.w);

            float rrv;
            if (t == 0) {
                rrv = fct_s[i] * 0.03125f;   // uniform r
            } else {
                float pacc = 0.f;
                #pragma unroll
                for (int j = 0; j < 8; ++j) {
                    float d = vv[j] - mu8[j];
                    pacc += d * d * is8[j];
                }
                pacc += __shfl_xor(pacc, 32, 64);    // combine q-halves
                float acc = kcv - pacc;
                // softmax over c (width-32; both halves identical)
                float mx = acc;
                mx = fmaxf(mx, __shfl_xor(mx, 1, 32));
                mx = fmaxf(mx, __shfl_xor(mx, 2, 32));
                mx = fmaxf(mx, __shfl_xor(mx, 4, 32));
                mx = fmaxf(mx, __shfl_xor(mx, 8, 32));
                mx = fmaxf(mx, __shfl_xor(mx, 16, 32));
                float e = expf(acc - mx);
                float se = e;
                se += __shfl_xor(se, 1, 32);
                se += __shfl_xor(se, 2, 32);
                se += __shfl_xor(se, 4, 32);
                se += __shfl_xor(se, 8, 32);
                se += __shfl_xor(se, 16, 32);
                rrv = (e / se) * fct_s[i];
            }

            s0 += rrv;
            #pragma unroll
            for (int j = 0; j < 8; ++j) {
                s1[j] += rrv * vv[j];
                s2[j] += rrv * vv[j] * vv[j];
            }
        }

        // per-wave partials -> LDS (stride 17: 2-way bank alias = free)
        {
            float* dst = &red_s[(wv * 64 + lane) * 17];
            dst[0] = s0;
            #pragma unroll
            for (int j = 0; j < 8; ++j) { dst[1 + j] = s1[j]; dst[9 + j] = s2[j]; }
        }
        __syncthreads();

        // final 16-way reduce + mu/sigma (thread = (c2,q2))
        if (tid < 512) {
            int c2 = tid >> 4, q2 = tid & 15;
            int qh2 = q2 >> 3, j2 = q2 & 7;
            float S0 = 0.f, S1 = 0.f, S2 = 0.f;
            #pragma unroll
            for (int wvi = 0; wvi < 16; ++wvi) {
                S0 += red_s[(wvi * 64 + c2) * 17];
                const float* sp = &red_s[(wvi * 64 + qh2 * 32 + c2) * 17];
                S1 += sp[1 + j2];
                S2 += sp[9 + j2];
            }
            if (q2 == 0) rsum_s[c2] = S0;
            float invr = 1.0f / (S0 + EPSV);
            float w0  = S0 * invr;
            float m   = S1 * invr;
            float s2p = S2 * invr;
            float sig = s2p - m * m * (2.0f - w0);   // == sum coeff*(v-mu)^2
            sig = fmaxf(sig + EPSV, 1e-4f);
            float hl = 0.5f * logf(sig);
            mu_s[c2 * 17 + q2]   = m;
            hlog_s[c2 * 17 + q2] = hl;
            i2ss_s[c2 * 17 + q2] = 1.0f / (2.0f * sig);
        }
        __syncthreads();

        // a_out + per-c ln_p constant
        if (tid < 32) {
            float cs = 0.f, shl = 0.f;
            float bu = beta_u[tid];
            #pragma unroll
            for (int q = 0; q < 16; ++q) { float hl = hlog_s[tid * 17 + q]; shl += hl; cs += bu + hl; }
            cs *= rsum_s[tid];
            float arg = LAMBDAV * (beta_a[tid] - cs);
            float ao  = 1.0f / (1.0f + expf(-arg));
            ao = fminf(fmaxf(ao, 1e-4f), 1.0f - 1e-4f);
            aout_s[tid] = ao;
            kc_s[tid]   = logf(ao + EPSV) - shl - 8.0f * LN_2PI;
        }
        __syncthreads();
    }

    // epilogue (fp32): p_out [0,65536) | a_out [65536,69632) | out [69632,139264)
    if (tid < 512) {
        int c2 = tid >> 4, q2 = tid & 15;
        float mu = mu_s[c2 * 17 + q2];
        if (isnan(mu)) mu = 0.f;
        mu = fminf(fmaxf(mu, -10000.f), 10000.f);
        out[(size_t)n * 512 + tid] = mu;
        out[69632 + (size_t)n * 544 + tid] = mu;
        if (tid < 32) {
            float ao = aout_s[tid];
            if (isnan(ao)) ao = 0.5f;
            out[65536 + n * 32 + tid] = ao;
            out[69632 + n * 544 + 512 + tid] = ao;
        }
    }
}

extern "C" void kernel_launch(void* const* d_in, const int* in_sizes, int n_in,
                              void* d_out, int out_size, void* d_ws, size_t ws_size,
                              hipStream_t stream) {
    const float* x  = (const float*)d_in[0];
    const float* w  = (const float*)d_in[1];
    const float* bu = (const float*)d_in[2];
    const float* ba = (const float*)d_in[3];
    float* out = (float*)d_out;
    __hip_bfloat16* v = (__hip_bfloat16*)d_ws;  // 128*288*512 bf16 = 37.7 MB

    const size_t per_n = (size_t)288 * 512 * sizeof(__hip_bfloat16); // 294912 B
    int CN = (int)(ws_size / per_n);
    if (CN < 1)   CN = 1;
    if (CN > 128) CN = 128;

    for (int ncur = 0; ncur < 128; ncur += CN) {
        int cnt = (128 - ncur < CN) ? (128 - ncur) : CN;
        conv_v_kernel<<<dim3(288, (cnt + 31) / 32), dim3(256), 0, stream>>>(
            x, w, v, ncur, cnt);
        em_routing_kernel<<<dim3(cnt), dim3(1024), 0, stream>>>(
            x, (const unsigned short*)v, bu, ba, out, ncur);
    }
}